// Round 14
// baseline (1307.246 us; speedup 1.0000x reference)
//
#include <hip/hip_runtime.h>
#include <hip/hip_bf16.h>
#include <cstdint>

using u16 = unsigned short;
typedef short s16x8 __attribute__((ext_vector_type(8)));
typedef float f32x4 __attribute__((ext_vector_type(4)));

// ---------- helpers ----------
__device__ __forceinline__ float b2f(u16 b) {
    union { unsigned u; float f; } z; z.u = ((unsigned)b) << 16; return z.f;
}
__device__ __forceinline__ u16 f2b(float f) {
    union { float f; unsigned u; } z; z.f = f;
    return (u16)((z.u + 0x7fffu + ((z.u >> 16) & 1u)) >> 16);
}
// libm erff: R12 proved ocml's erff beats a hand-rolled A&S poly whose
// __frcp_rn lowered to the full correctly-rounded divide sequence.
__device__ __forceinline__ float gelu_f(float x) {
    return 0.5f * x * (1.0f + erff(x * 0.70710678118654752440f));
}
__device__ __forceinline__ void gl2lds16(const void* g, void* l) {
    __builtin_amdgcn_global_load_lds(
        (const __attribute__((address_space(1))) void*)g,
        (__attribute__((address_space(3))) void*)l, 16, 0, 0);
}

enum { F_BIAS = 1, F_GELU = 2, F_RANK3 = 4, F_RESIDH = 8,
       F_DEG = 16, F_OUTF = 32, F_OUTH = 64 };

// ---------- GEMM 128x128, BK=64: C = epi(A[Mx512] @ Bt[Nx512]^T) ----------
// R11-verified: bank conflicts 0 (chunk-XOR swizzle, rule #21 both-sides),
// T1 bijective XCD swizzle (FETCH 202->37 MB), BK=64 halves barrier drains.
// launch_bounds (256,5): 5 blocks/CU (5 x 32KB = 160KB LDS exactly; 64 VGPR
// << 102 budget) — R4-proven lever, was left at 4 since then. +25% resident
// waves to overlap the per-block vmcnt(0)+barrier drain.
template<int EPI>
__global__ __launch_bounds__(256, 5) void gemm_k(
    const u16* __restrict__ A, const u16* __restrict__ Bt,
    float* __restrict__ Cf, u16* __restrict__ Ch,
    const u16* __restrict__ srcH,
    const float* __restrict__ bias, const float* __restrict__ bias2,
    const int* __restrict__ deg, const float* __restrict__ river,
    const float* __restrict__ w1tail, int Mreal, int ldh, int gxShift,
    float degScale)
{
    __shared__ __align__(16) u16 As[128 * 64];   // 16 KB
    __shared__ __align__(16) u16 Bs[128 * 64];   // 16 KB

    const int nwg  = gridDim.x;
    const int orig = blockIdx.x;
    const int xcd  = orig & 7;
    const int i8   = orig >> 3;
    const int q    = nwg >> 3;
    const int rm   = nwg & 7;
    const int swz  = (xcd < rm) ? (xcd * (q + 1) + i8)
                                : (rm * (q + 1) + (xcd - rm) * q + i8);
    const int rowblk = swz >> gxShift;
    const int colblk = swz & ((1 << gxShift) - 1);

    const int tid  = threadIdx.x;
    const int lane = tid & 63;
    const int wid  = tid >> 6;     // 0..3
    const int wr   = wid >> 1;
    const int wc   = wid & 1;
    const int fr   = lane & 15;
    const int fq   = lane >> 4;

    const int  srowl = lane >> 3;                       // 0..7 within issue
    const long gchnk = (long)(((lane & 7) ^ (srowl & 7)) << 3);  // elem offset
    const long abase = (long)rowblk * 128 + (wid << 5) + srowl;
    const long bbase = (long)colblk * 128 + (wid << 5) + srowl;
    u16* asw = As + (wid << 11);                        // wid*32*64 elems
    u16* bsw = Bs + (wid << 11);

    f32x4 acc[4][4];
#pragma unroll
    for (int m = 0; m < 4; m++)
#pragma unroll
        for (int n = 0; n < 4; n++) { f32x4 z = {0.f, 0.f, 0.f, 0.f}; acc[m][n] = z; }

    for (int kt = 0; kt < 8; kt++) {
        const long ko = (long)(kt << 6) + gchnk;
#pragma unroll
        for (int j = 0; j < 4; j++) {
            gl2lds16(A  + (abase + (j << 3)) * 512 + ko, asw + (j << 9));
            gl2lds16(Bt + (bbase + (j << 3)) * 512 + ko, bsw + (j << 9));
        }
        __syncthreads();

#pragma unroll
        for (int ks = 0; ks < 2; ks++) {
            const int sc = ((((ks << 2) + fq) ^ (fr & 7)) << 3);  // swizzled chunk
            s16x8 af[4], bf[4];
#pragma unroll
            for (int m = 0; m < 4; m++)
                af[m] = *(const s16x8*)(As + (((wr << 6) + (m << 4) + fr) << 6) + sc);
#pragma unroll
            for (int n = 0; n < 4; n++)
                bf[n] = *(const s16x8*)(Bs + (((wc << 6) + (n << 4) + fr) << 6) + sc);
#pragma unroll
            for (int m = 0; m < 4; m++)
#pragma unroll
                for (int n = 0; n < 4; n++)
                    acc[m][n] = __builtin_amdgcn_mfma_f32_16x16x32_bf16(af[m], bf[n], acc[m][n], 0, 0, 0);
        }
        __syncthreads();
    }

    const int colbase = (colblk << 7) + (wc << 6);
#pragma unroll
    for (int m = 0; m < 4; m++) {
        const int row0 = (rowblk << 7) + (wr << 6) + (m << 4) + (fq << 2);
#pragma unroll
        for (int rI = 0; rI < 4; rI++) {
            const int rr = row0 + rI;
            const bool real = rr < Mreal;
            float rv0 = 0.f, rv1 = 0.f, rv2 = 0.f;
            if constexpr (EPI & F_RANK3) {
                if (real) { rv0 = river[rr * 3]; rv1 = river[rr * 3 + 1]; rv2 = river[rr * 3 + 2]; }
            }
            float dg = 0.f;
            if constexpr (EPI & F_DEG) { if (real) dg = (float)deg[rr] * degScale; }
#pragma unroll
            for (int n = 0; n < 4; n++) {
                const int col = colbase + (n << 4) + fr;
                float v = acc[m][n][rI];
                if constexpr (EPI & F_BIAS)   v += bias[col];
                if constexpr (EPI & F_RANK3)  v += rv0 * w1tail[col] + rv1 * w1tail[512 + col] + rv2 * w1tail[1024 + col];
                if constexpr (EPI & F_GELU)   v = gelu_f(v);
                if constexpr (EPI & F_RESIDH) v += b2f(srcH[(long)rr * ldh + col]);
                if constexpr (EPI & F_DEG)    v += dg * bias2[col];
                if constexpr (EPI & F_OUTF)   { if (real) Cf[(long)rr * 512 + col] = v; }
                if constexpr (EPI & F_OUTH)   Ch[(long)rr * ldh + col] = f2b(v);
            }
        }
    }
}

// ---------- CSR build ----------
__global__ __launch_bounds__(256) void deg_k(const int* __restrict__ ed, int* __restrict__ deg, int nE)
{
    const int e = blockIdx.x * 256 + threadIdx.x;
    if (e < nE) atomicAdd(&deg[ed[2 * e + 1]], 1);
}

__global__ __launch_bounds__(256) void scan1_k(
    const int* __restrict__ deg, int* __restrict__ rowptr,
    int* __restrict__ partials, int n)
{
    __shared__ int tmp[256];
    const int tid = threadIdx.x;
    const int gid = blockIdx.x * 256 + tid;
    const int v = (gid < n) ? deg[gid] : 0;
    tmp[tid] = v;
    __syncthreads();
#pragma unroll
    for (int ofs = 1; ofs < 256; ofs <<= 1) {
        int t = (tid >= ofs) ? tmp[tid - ofs] : 0;
        __syncthreads();
        tmp[tid] += t;
        __syncthreads();
    }
    if (gid < n) rowptr[gid] = tmp[tid] - v;
    if (tid == 255) partials[blockIdx.x] = tmp[255];
}

__global__ __launch_bounds__(256) void scan2_k(int* __restrict__ partials, int nb)
{
    __shared__ int tmp[256];
    const int tid = threadIdx.x;
    const int v = (tid < nb) ? partials[tid] : 0;
    tmp[tid] = v;
    __syncthreads();
#pragma unroll
    for (int ofs = 1; ofs < 256; ofs <<= 1) {
        int t = (tid >= ofs) ? tmp[tid - ofs] : 0;
        __syncthreads();
        tmp[tid] += t;
        __syncthreads();
    }
    if (tid < nb) partials[tid] = tmp[tid] - v;
}

__global__ __launch_bounds__(256) void scan3_k(
    int* __restrict__ rowptr, const int* __restrict__ partials, int n)
{
    const int gid = blockIdx.x * 256 + threadIdx.x;
    if (gid < n) rowptr[gid] += partials[blockIdx.x];
}

__global__ __launch_bounds__(256) void scat_k(
    const int* __restrict__ ed, const int* __restrict__ rowptr,
    int* __restrict__ cursor, int* __restrict__ csr, int nE)
{
    const int e = blockIdx.x * 256 + threadIdx.x;
    if (e >= nE) return;
    const int t = ed[2 * e + 1];
    const int p = atomicAdd(&cursor[t], 1);
    csr[rowptr[t] + p] = ed[2 * e];
}

// ---------- gather: Hg[t] = bf16( sum_{s in in(t)} gelu(A[s] + B[t] + bm1) ) ----------
// 1-deep software prefetch (R13: small but non-negative gain, kept).
__global__ __launch_bounds__(256) void gather_k(
    const int* __restrict__ rowptr, const int* __restrict__ degv,
    const int* __restrict__ csr, const u16* __restrict__ AB,
    const float* __restrict__ bm1, u16* __restrict__ Hg, int nNodes)
{
    const int t = (blockIdx.x << 2) + (threadIdx.x >> 6);
    if (t >= nNodes) return;
    const int lane = threadIdx.x & 63;
    const int c = lane << 3;
    float acc[8] = {0.f, 0.f, 0.f, 0.f, 0.f, 0.f, 0.f, 0.f};
    const int d = degv[t];
    if (d > 0) {
        s16x8 bv = *(const s16x8*)(AB + (long)t * 1024 + 512 + c);
        const float4* bmv = (const float4*)(bm1 + c);
        float4 q0 = bmv[0], q1 = bmv[1];
        float base[8] = { q0.x, q0.y, q0.z, q0.w, q1.x, q1.y, q1.z, q1.w };
#pragma unroll
        for (int j = 0; j < 8; j++) base[j] += b2f((u16)bv[j]);
        const int p0 = rowptr[t];
        s16x8 av = *(const s16x8*)(AB + (long)csr[p0] * 1024 + c);
        for (int i = 0; i < d; i++) {
            s16x8 nxt = av;
            if (i + 1 < d)
                nxt = *(const s16x8*)(AB + (long)csr[p0 + i + 1] * 1024 + c);
#pragma unroll
            for (int j = 0; j < 8; j++) acc[j] += gelu_f(b2f((u16)av[j]) + base[j]);
            av = nxt;
        }
    }
    s16x8 o;
#pragma unroll
    for (int j = 0; j < 8; j++) o[j] = (short)f2b(acc[j]);
    *(s16x8*)(Hg + (long)t * 512 + c) = o;
}

// ---------- f32 -> bf16 (flat, region beyond nSrc zero-filled) ----------
__global__ __launch_bounds__(256) void cvt_pad_k(
    const float* __restrict__ src, u16* __restrict__ dst, long nSrc, long nTot)
{
    const long i = ((long)blockIdx.x * 256 + threadIdx.x) * 8;
    if (i >= nTot) return;
    s16x8 v;
    if (i + 8 <= nSrc) {
        const float4* s4 = (const float4*)(src + i);
        float4 a = s4[0], b = s4[1];
        v[0] = (short)f2b(a.x); v[1] = (short)f2b(a.y); v[2] = (short)f2b(a.z); v[3] = (short)f2b(a.w);
        v[4] = (short)f2b(b.x); v[5] = (short)f2b(b.y); v[6] = (short)f2b(b.z); v[7] = (short)f2b(b.w);
    } else {
#pragma unroll
        for (int j = 0; j < 8; j++) v[j] = (i + j < nSrc) ? (short)f2b(src[i + j]) : (short)0;
    }
    *(s16x8*)(dst + i) = v;
}

// ---------- weight transpose + convert: Wt[n*K+k] = bf16(W[(k+off)*N + n]) ----------
__global__ __launch_bounds__(256) void wtrans_k(
    const float* __restrict__ W, u16* __restrict__ Wt, int K, int N, int rowOff)
{
    const int idx = blockIdx.x * 256 + threadIdx.x;
    if (idx >= K * N) return;
    const int n = idx / K, k = idx % K;
    Wt[idx] = f2b(W[(long)(k + rowOff) * N + n]);
}

extern "C" void kernel_launch(void* const* d_in, const int* in_sizes, int n_in,
                              void* d_out, int out_size, void* d_ws, size_t ws_size,
                              hipStream_t stream)
{
    const float* nodef = (const float*)d_in[0];
    const float* river = (const float*)d_in[1];
    const int*   edges = (const int*)d_in[2];
    const float* W1  = (const float*)d_in[3];
    const float* b1  = (const float*)d_in[4];
    const float* W2  = (const float*)d_in[5];
    const float* b2  = (const float*)d_in[6];
    const float* Wm1 = (const float*)d_in[7];
    const float* bm1 = (const float*)d_in[8];
    const float* Wm2 = (const float*)d_in[9];
    const float* bm2 = (const float*)d_in[10];
    float* out = (float*)d_out;
    (void)n_in; (void)out_size;

    const int M = 50000, Mpad = 50048, H = 512;
    const int nE = in_sizes[2] / 2;
    const size_t nElem = (size_t)Mpad * H;
    const size_t nOut  = (size_t)M * H;

    char* ws = (char*)d_ws;
    size_t off = 0;
    auto alloc = [&](size_t bytes) { void* p = ws + off; off += (bytes + 255) & ~(size_t)255; return p; };
    u16* feats16 = (u16*)alloc(nElem * 2);            // running features (bf16 residual carrier)
    u16* AB16    = (u16*)alloc(nElem * 4);            // [Mpad][1024]: A | B (nf16 early)
    u16* Hg16    = (u16*)alloc(nElem * 2);            // gather output / h1
    u16* W1t     = (u16*)alloc(512 * 512 * 2);
    u16* W2t     = (u16*)alloc(512 * 512 * 2);
    u16* Wm1ct   = (u16*)alloc(1024 * 512 * 2);
    u16* Wm2t    = (u16*)alloc(512 * 512 * 2);
    int* deg     = (int*)alloc((size_t)Mpad * 4);
    int* rowptr  = (int*)alloc((size_t)Mpad * 4);
    int* cursor  = (int*)alloc((size_t)Mpad * 4);
    int* csr     = (int*)alloc((size_t)nE * 4);
    int* partials= (int*)alloc(256 * 4);
    const size_t NEED = off;                          // ~209 MB (confirmed fits)

    if (ws_size < NEED) return;                       // tripwire: clean absmax fail

    const int scanBlocks = (Mpad + 255) / 256;        // 196
    const int MB = Mpad / 128;                        // 391
    const dim3 g512(MB * 4, 1, 1);                    // gxShift=2
    const dim3 g1024(MB * 8, 1, 1);                   // gxShift=3
    const dim3 gblk(256, 1, 1);
    const int cvtBlocks = (int)(nElem / 8 / 256);

    // CSR build (edges fixed; rebuilt every call for determinism)
    hipMemsetAsync(deg, 0, (size_t)Mpad * 4, stream);
    hipMemsetAsync(cursor, 0, (size_t)Mpad * 4, stream);
    deg_k<<<dim3((nE + 255) / 256), gblk, 0, stream>>>(edges, deg, nE);
    scan1_k<<<dim3(scanBlocks), gblk, 0, stream>>>(deg, rowptr, partials, Mpad);
    scan2_k<<<dim3(1), gblk, 0, stream>>>(partials, scanBlocks);
    scan3_k<<<dim3(scanBlocks), gblk, 0, stream>>>(rowptr, partials, Mpad);
    scat_k<<<dim3((nE + 255) / 256), gblk, 0, stream>>>(edges, rowptr, cursor, csr, nE);

    // weights -> transposed bf16
    wtrans_k<<<dim3(1024), gblk, 0, stream>>>(W1,  W1t,             512, 512, 0);
    wtrans_k<<<dim3(1024), gblk, 0, stream>>>(W2,  W2t,             512, 512, 0);
    wtrans_k<<<dim3(1024), gblk, 0, stream>>>(Wm1, Wm1ct,           512, 512, 0);
    wtrans_k<<<dim3(1024), gblk, 0, stream>>>(Wm1, Wm1ct + 512*512, 512, 512, 512);
    wtrans_k<<<dim3(1024), gblk, 0, stream>>>(Wm2, Wm2t,            512, 512, 0);

    // node_features -> bf16 (flat [Mpad][512] in AB16 first half)
    cvt_pad_k<<<dim3(cvtBlocks), gblk, 0, stream>>>(nodef, AB16, (long)nOut, (long)nElem);

    // h1 = gelu(x @ W1 + b1 + river term) -> Hg16
    gemm_k<F_BIAS | F_RANK3 | F_GELU | F_OUTH><<<g512, gblk, 0, stream>>>(
        AB16, W1t, nullptr, Hg16, nullptr, b1, nullptr, nullptr, river, W1 + 512 * 512, M, 512, 2, 1.f);
    // feats16 = h1 @ W2 + b2  (bf16 only)
    gemm_k<F_BIAS | F_OUTH><<<g512, gblk, 0, stream>>>(
        Hg16, W2t, nullptr, feats16, nullptr, b2, nullptr, nullptr, nullptr, nullptr, M, 512, 2, 1.f);

    for (int r = 0; r < 3; r++) {
        // AB = feats @ [Wm1_top | Wm1_bot]  (N=1024 combined)
        gemm_k<F_OUTH><<<g1024, gblk, 0, stream>>>(
            feats16, Wm1ct, nullptr, AB16, nullptr, nullptr, nullptr, nullptr, nullptr, nullptr, M, 1024, 3, 1.f);
        // Hg[t] = sum_in gelu(A[s] + B[t] + bm1)
        gather_k<<<dim3(Mpad / 4), gblk, 0, stream>>>(rowptr, deg, csr, AB16, bm1, Hg16, Mpad);
        // feats = feats + Hg @ Wm2 + deg * bm2
        if (r < 2)
            gemm_k<F_RESIDH | F_DEG | F_OUTH><<<g512, gblk, 0, stream>>>(
                Hg16, Wm2t, nullptr, feats16, feats16, nullptr, bm2, deg, nullptr, nullptr, M, 512, 2, 1.f);
        else
            gemm_k<F_RESIDH | F_DEG | F_OUTF><<<g512, gblk, 0, stream>>>(
                Hg16, Wm2t, out, nullptr, feats16, nullptr, bm2, deg, nullptr, nullptr, M, 512, 2, 1.f);
    }
}

// Round 15
// 659.035 us; speedup vs baseline: 1.9836x; 1.9836x over previous
//
#include <hip/hip_runtime.h>
#include <hip/hip_bf16.h>
#include <cstdint>

using u16 = unsigned short;
typedef short s16x8 __attribute__((ext_vector_type(8)));
typedef float f32x4 __attribute__((ext_vector_type(4)));

// ---------- helpers ----------
__device__ __forceinline__ float b2f(u16 b) {
    union { unsigned u; float f; } z; z.u = ((unsigned)b) << 16; return z.f;
}
__device__ __forceinline__ u16 f2b(float f) {
    union { float f; unsigned u; } z; z.f = f;
    return (u16)((z.u + 0x7fffu + ((z.u >> 16) & 1u)) >> 16);
}
// libm erff: R12 proved ocml's erff beats a hand-rolled A&S poly whose
// __frcp_rn lowered to the full correctly-rounded divide sequence.
__device__ __forceinline__ float gelu_f(float x) {
    return 0.5f * x * (1.0f + erff(x * 0.70710678118654752440f));
}
__device__ __forceinline__ void gl2lds16(const void* g, void* l) {
    __builtin_amdgcn_global_load_lds(
        (const __attribute__((address_space(1))) void*)g,
        (__attribute__((address_space(3))) void*)l, 16, 0, 0);
}

enum { F_BIAS = 1, F_GELU = 2, F_RANK3 = 4, F_RESIDH = 8,
       F_DEG = 16, F_OUTF = 32, F_OUTH = 64 };

// ---------- GEMM 128x128, BK=64: C = epi(A[Mx512] @ Bt[Nx512]^T) ----------
// R11-verified: bank conflicts 0 (chunk-XOR swizzle, rule #21 both-sides),
// T1 bijective XCD swizzle (FETCH 202->37 MB), BK=64 halves barrier drains.
// launch_bounds (256,4): unified VGPR+AGPR need ~128/wave (64 arch + 64 acc);
// 512/4 = 128 exactly fits. R14 proved (256,5) -> 102 budget -> scratch spill
// (WRITE 137->377 MB, 2x slower). Do not raise.
template<int EPI>
__global__ __launch_bounds__(256, 4) void gemm_k(
    const u16* __restrict__ A, const u16* __restrict__ Bt,
    float* __restrict__ Cf, u16* __restrict__ Ch,
    const u16* __restrict__ srcH,
    const float* __restrict__ bias, const float* __restrict__ bias2,
    const int* __restrict__ deg, const float* __restrict__ river,
    const float* __restrict__ w1tail, int Mreal, int ldh, int gxShift,
    float degScale)
{
    __shared__ __align__(16) u16 As[128 * 64];   // 16 KB
    __shared__ __align__(16) u16 Bs[128 * 64];   // 16 KB

    const int nwg  = gridDim.x;
    const int orig = blockIdx.x;
    const int xcd  = orig & 7;
    const int i8   = orig >> 3;
    const int q    = nwg >> 3;
    const int rm   = nwg & 7;
    const int swz  = (xcd < rm) ? (xcd * (q + 1) + i8)
                                : (rm * (q + 1) + (xcd - rm) * q + i8);
    const int rowblk = swz >> gxShift;
    const int colblk = swz & ((1 << gxShift) - 1);

    const int tid  = threadIdx.x;
    const int lane = tid & 63;
    const int wid  = tid >> 6;     // 0..3
    const int wr   = wid >> 1;
    const int wc   = wid & 1;
    const int fr   = lane & 15;
    const int fq   = lane >> 4;

    const int  srowl = lane >> 3;                       // 0..7 within issue
    const long gchnk = (long)(((lane & 7) ^ (srowl & 7)) << 3);  // elem offset
    const long abase = (long)rowblk * 128 + (wid << 5) + srowl;
    const long bbase = (long)colblk * 128 + (wid << 5) + srowl;
    u16* asw = As + (wid << 11);                        // wid*32*64 elems
    u16* bsw = Bs + (wid << 11);

    f32x4 acc[4][4];
#pragma unroll
    for (int m = 0; m < 4; m++)
#pragma unroll
        for (int n = 0; n < 4; n++) { f32x4 z = {0.f, 0.f, 0.f, 0.f}; acc[m][n] = z; }

    for (int kt = 0; kt < 8; kt++) {
        const long ko = (long)(kt << 6) + gchnk;
#pragma unroll
        for (int j = 0; j < 4; j++) {
            gl2lds16(A  + (abase + (j << 3)) * 512 + ko, asw + (j << 9));
            gl2lds16(Bt + (bbase + (j << 3)) * 512 + ko, bsw + (j << 9));
        }
        __syncthreads();

#pragma unroll
        for (int ks = 0; ks < 2; ks++) {
            const int sc = ((((ks << 2) + fq) ^ (fr & 7)) << 3);  // swizzled chunk
            s16x8 af[4], bf[4];
#pragma unroll
            for (int m = 0; m < 4; m++)
                af[m] = *(const s16x8*)(As + (((wr << 6) + (m << 4) + fr) << 6) + sc);
#pragma unroll
            for (int n = 0; n < 4; n++)
                bf[n] = *(const s16x8*)(Bs + (((wc << 6) + (n << 4) + fr) << 6) + sc);
#pragma unroll
            for (int m = 0; m < 4; m++)
#pragma unroll
                for (int n = 0; n < 4; n++)
                    acc[m][n] = __builtin_amdgcn_mfma_f32_16x16x32_bf16(af[m], bf[n], acc[m][n], 0, 0, 0);
        }
        __syncthreads();
    }

    const int colbase = (colblk << 7) + (wc << 6);
#pragma unroll
    for (int m = 0; m < 4; m++) {
        const int row0 = (rowblk << 7) + (wr << 6) + (m << 4) + (fq << 2);
#pragma unroll
        for (int rI = 0; rI < 4; rI++) {
            const int rr = row0 + rI;
            const bool real = rr < Mreal;
            float rv0 = 0.f, rv1 = 0.f, rv2 = 0.f;
            if constexpr (EPI & F_RANK3) {
                if (real) { rv0 = river[rr * 3]; rv1 = river[rr * 3 + 1]; rv2 = river[rr * 3 + 2]; }
            }
            float dg = 0.f;
            if constexpr (EPI & F_DEG) { if (real) dg = (float)deg[rr] * degScale; }
#pragma unroll
            for (int n = 0; n < 4; n++) {
                const int col = colbase + (n << 4) + fr;
                float v = acc[m][n][rI];
                if constexpr (EPI & F_BIAS)   v += bias[col];
                if constexpr (EPI & F_RANK3)  v += rv0 * w1tail[col] + rv1 * w1tail[512 + col] + rv2 * w1tail[1024 + col];
                if constexpr (EPI & F_GELU)   v = gelu_f(v);
                if constexpr (EPI & F_RESIDH) v += b2f(srcH[(long)rr * ldh + col]);
                if constexpr (EPI & F_DEG)    v += dg * bias2[col];
                if constexpr (EPI & F_OUTF)   { if (real) Cf[(long)rr * 512 + col] = v; }
                if constexpr (EPI & F_OUTH)   Ch[(long)rr * ldh + col] = f2b(v);
            }
        }
    }
}

// ---------- CSR build ----------
__global__ __launch_bounds__(256) void deg_k(const int* __restrict__ ed, int* __restrict__ deg, int nE)
{
    const int e = blockIdx.x * 256 + threadIdx.x;
    if (e < nE) atomicAdd(&deg[ed[2 * e + 1]], 1);
}

__global__ __launch_bounds__(256) void scan1_k(
    const int* __restrict__ deg, int* __restrict__ rowptr,
    int* __restrict__ partials, int n)
{
    __shared__ int tmp[256];
    const int tid = threadIdx.x;
    const int gid = blockIdx.x * 256 + tid;
    const int v = (gid < n) ? deg[gid] : 0;
    tmp[tid] = v;
    __syncthreads();
#pragma unroll
    for (int ofs = 1; ofs < 256; ofs <<= 1) {
        int t = (tid >= ofs) ? tmp[tid - ofs] : 0;
        __syncthreads();
        tmp[tid] += t;
        __syncthreads();
    }
    if (gid < n) rowptr[gid] = tmp[tid] - v;
    if (tid == 255) partials[blockIdx.x] = tmp[255];
}

__global__ __launch_bounds__(256) void scan2_k(int* __restrict__ partials, int nb)
{
    __shared__ int tmp[256];
    const int tid = threadIdx.x;
    const int v = (tid < nb) ? partials[tid] : 0;
    tmp[tid] = v;
    __syncthreads();
#pragma unroll
    for (int ofs = 1; ofs < 256; ofs <<= 1) {
        int t = (tid >= ofs) ? tmp[tid - ofs] : 0;
        __syncthreads();
        tmp[tid] += t;
        __syncthreads();
    }
    if (tid < nb) partials[tid] = tmp[tid] - v;
}

__global__ __launch_bounds__(256) void scan3_k(
    int* __restrict__ rowptr, const int* __restrict__ partials, int n)
{
    const int gid = blockIdx.x * 256 + threadIdx.x;
    if (gid < n) rowptr[gid] += partials[blockIdx.x];
}

__global__ __launch_bounds__(256) void scat_k(
    const int* __restrict__ ed, const int* __restrict__ rowptr,
    int* __restrict__ cursor, int* __restrict__ csr, int nE)
{
    const int e = blockIdx.x * 256 + threadIdx.x;
    if (e >= nE) return;
    const int t = ed[2 * e + 1];
    const int p = atomicAdd(&cursor[t], 1);
    csr[rowptr[t] + p] = ed[2 * e];
}

// ---------- gather: Hg[t] = bf16( sum_{s in in(t)} gelu(A[s] + B[t] + bm1) ) ----------
// 1-deep software prefetch (R13: small but non-negative gain, kept).
__global__ __launch_bounds__(256) void gather_k(
    const int* __restrict__ rowptr, const int* __restrict__ degv,
    const int* __restrict__ csr, const u16* __restrict__ AB,
    const float* __restrict__ bm1, u16* __restrict__ Hg, int nNodes)
{
    const int t = (blockIdx.x << 2) + (threadIdx.x >> 6);
    if (t >= nNodes) return;
    const int lane = threadIdx.x & 63;
    const int c = lane << 3;
    float acc[8] = {0.f, 0.f, 0.f, 0.f, 0.f, 0.f, 0.f, 0.f};
    const int d = degv[t];
    if (d > 0) {
        s16x8 bv = *(const s16x8*)(AB + (long)t * 1024 + 512 + c);
        const float4* bmv = (const float4*)(bm1 + c);
        float4 q0 = bmv[0], q1 = bmv[1];
        float base[8] = { q0.x, q0.y, q0.z, q0.w, q1.x, q1.y, q1.z, q1.w };
#pragma unroll
        for (int j = 0; j < 8; j++) base[j] += b2f((u16)bv[j]);
        const int p0 = rowptr[t];
        s16x8 av = *(const s16x8*)(AB + (long)csr[p0] * 1024 + c);
        for (int i = 0; i < d; i++) {
            s16x8 nxt = av;
            if (i + 1 < d)
                nxt = *(const s16x8*)(AB + (long)csr[p0 + i + 1] * 1024 + c);
#pragma unroll
            for (int j = 0; j < 8; j++) acc[j] += gelu_f(b2f((u16)av[j]) + base[j]);
            av = nxt;
        }
    }
    s16x8 o;
#pragma unroll
    for (int j = 0; j < 8; j++) o[j] = (short)f2b(acc[j]);
    *(s16x8*)(Hg + (long)t * 512 + c) = o;
}

// ---------- f32 -> bf16 (flat, region beyond nSrc zero-filled) ----------
__global__ __launch_bounds__(256) void cvt_pad_k(
    const float* __restrict__ src, u16* __restrict__ dst, long nSrc, long nTot)
{
    const long i = ((long)blockIdx.x * 256 + threadIdx.x) * 8;
    if (i >= nTot) return;
    s16x8 v;
    if (i + 8 <= nSrc) {
        const float4* s4 = (const float4*)(src + i);
        float4 a = s4[0], b = s4[1];
        v[0] = (short)f2b(a.x); v[1] = (short)f2b(a.y); v[2] = (short)f2b(a.z); v[3] = (short)f2b(a.w);
        v[4] = (short)f2b(b.x); v[5] = (short)f2b(b.y); v[6] = (short)f2b(b.z); v[7] = (short)f2b(b.w);
    } else {
#pragma unroll
        for (int j = 0; j < 8; j++) v[j] = (i + j < nSrc) ? (short)f2b(src[i + j]) : (short)0;
    }
    *(s16x8*)(dst + i) = v;
}

// ---------- weight transpose + convert: Wt[n*K+k] = bf16(W[(k+off)*N + n]) ----------
__global__ __launch_bounds__(256) void wtrans_k(
    const float* __restrict__ W, u16* __restrict__ Wt, int K, int N, int rowOff)
{
    const int idx = blockIdx.x * 256 + threadIdx.x;
    if (idx >= K * N) return;
    const int n = idx / K, k = idx % K;
    Wt[idx] = f2b(W[(long)(k + rowOff) * N + n]);
}

extern "C" void kernel_launch(void* const* d_in, const int* in_sizes, int n_in,
                              void* d_out, int out_size, void* d_ws, size_t ws_size,
                              hipStream_t stream)
{
    const float* nodef = (const float*)d_in[0];
    const float* river = (const float*)d_in[1];
    const int*   edges = (const int*)d_in[2];
    const float* W1  = (const float*)d_in[3];
    const float* b1  = (const float*)d_in[4];
    const float* W2  = (const float*)d_in[5];
    const float* b2  = (const float*)d_in[6];
    const float* Wm1 = (const float*)d_in[7];
    const float* bm1 = (const float*)d_in[8];
    const float* Wm2 = (const float*)d_in[9];
    const float* bm2 = (const float*)d_in[10];
    float* out = (float*)d_out;
    (void)n_in; (void)out_size;

    const int M = 50000, Mpad = 50048, H = 512;
    const int nE = in_sizes[2] / 2;
    const size_t nElem = (size_t)Mpad * H;
    const size_t nOut  = (size_t)M * H;

    char* ws = (char*)d_ws;
    size_t off = 0;
    auto alloc = [&](size_t bytes) { void* p = ws + off; off += (bytes + 255) & ~(size_t)255; return p; };
    u16* feats16 = (u16*)alloc(nElem * 2);            // running features (bf16 residual carrier)
    u16* AB16    = (u16*)alloc(nElem * 4);            // [Mpad][1024]: A | B (nf16 early)
    u16* Hg16    = (u16*)alloc(nElem * 2);            // gather output / h1
    u16* W1t     = (u16*)alloc(512 * 512 * 2);
    u16* W2t     = (u16*)alloc(512 * 512 * 2);
    u16* Wm1ct   = (u16*)alloc(1024 * 512 * 2);
    u16* Wm2t    = (u16*)alloc(512 * 512 * 2);
    int* deg     = (int*)alloc((size_t)Mpad * 4);
    int* rowptr  = (int*)alloc((size_t)Mpad * 4);
    int* cursor  = (int*)alloc((size_t)Mpad * 4);
    int* csr     = (int*)alloc((size_t)nE * 4);
    int* partials= (int*)alloc(256 * 4);
    const size_t NEED = off;                          // ~209 MB (confirmed fits)

    if (ws_size < NEED) return;                       // tripwire: clean absmax fail

    const int scanBlocks = (Mpad + 255) / 256;        // 196
    const int MB = Mpad / 128;                        // 391
    const dim3 g512(MB * 4, 1, 1);                    // gxShift=2
    const dim3 g1024(MB * 8, 1, 1);                   // gxShift=3
    const dim3 gblk(256, 1, 1);
    const int cvtBlocks = (int)(nElem / 8 / 256);

    // CSR build (edges fixed; rebuilt every call for determinism)
    hipMemsetAsync(deg, 0, (size_t)Mpad * 4, stream);
    hipMemsetAsync(cursor, 0, (size_t)Mpad * 4, stream);
    deg_k<<<dim3((nE + 255) / 256), gblk, 0, stream>>>(edges, deg, nE);
    scan1_k<<<dim3(scanBlocks), gblk, 0, stream>>>(deg, rowptr, partials, Mpad);
    scan2_k<<<dim3(1), gblk, 0, stream>>>(partials, scanBlocks);
    scan3_k<<<dim3(scanBlocks), gblk, 0, stream>>>(rowptr, partials, Mpad);
    scat_k<<<dim3((nE + 255) / 256), gblk, 0, stream>>>(edges, rowptr, cursor, csr, nE);

    // weights -> transposed bf16
    wtrans_k<<<dim3(1024), gblk, 0, stream>>>(W1,  W1t,             512, 512, 0);
    wtrans_k<<<dim3(1024), gblk, 0, stream>>>(W2,  W2t,             512, 512, 0);
    wtrans_k<<<dim3(1024), gblk, 0, stream>>>(Wm1, Wm1ct,           512, 512, 0);
    wtrans_k<<<dim3(1024), gblk, 0, stream>>>(Wm1, Wm1ct + 512*512, 512, 512, 512);
    wtrans_k<<<dim3(1024), gblk, 0, stream>>>(Wm2, Wm2t,            512, 512, 0);

    // node_features -> bf16 (flat [Mpad][512] in AB16 first half)
    cvt_pad_k<<<dim3(cvtBlocks), gblk, 0, stream>>>(nodef, AB16, (long)nOut, (long)nElem);

    // h1 = gelu(x @ W1 + b1 + river term) -> Hg16
    gemm_k<F_BIAS | F_RANK3 | F_GELU | F_OUTH><<<g512, gblk, 0, stream>>>(
        AB16, W1t, nullptr, Hg16, nullptr, b1, nullptr, nullptr, river, W1 + 512 * 512, M, 512, 2, 1.f);
    // feats16 = h1 @ W2 + b2  (bf16 only)
    gemm_k<F_BIAS | F_OUTH><<<g512, gblk, 0, stream>>>(
        Hg16, W2t, nullptr, feats16, nullptr, b2, nullptr, nullptr, nullptr, nullptr, M, 512, 2, 1.f);

    for (int r = 0; r < 3; r++) {
        // AB = feats @ [Wm1_top | Wm1_bot]  (N=1024 combined)
        gemm_k<F_OUTH><<<g1024, gblk, 0, stream>>>(
            feats16, Wm1ct, nullptr, AB16, nullptr, nullptr, nullptr, nullptr, nullptr, nullptr, M, 1024, 3, 1.f);
        // Hg[t] = sum_in gelu(A[s] + B[t] + bm1)
        gather_k<<<dim3(Mpad / 4), gblk, 0, stream>>>(rowptr, deg, csr, AB16, bm1, Hg16, Mpad);
        // feats = feats + Hg @ Wm2 + deg * bm2
        if (r < 2)
            gemm_k<F_RESIDH | F_DEG | F_OUTH><<<g512, gblk, 0, stream>>>(
                Hg16, Wm2t, nullptr, feats16, feats16, nullptr, bm2, deg, nullptr, nullptr, M, 512, 2, 1.f);
        else
            gemm_k<F_RESIDH | F_DEG | F_OUTF><<<g512, gblk, 0, stream>>>(
                Hg16, Wm2t, out, nullptr, feats16, nullptr, bm2, deg, nullptr, nullptr, M, 512, 2, 1.f);
    }
}